// Round 19
// baseline (131.194 us; speedup 1.0000x reference)
//
#include <hip/hip_runtime.h>
#include <math.h>

#define B_ 8
#define C_ 256
#define N_ 4096
#define K_ 1024
#define NH_ 8
#define HD_ 32

typedef __attribute__((ext_vector_type(8))) short short8;     // 8 x bf16 (4 VGPRs)
typedef __attribute__((ext_vector_type(8))) _Float16 half8;   // 8 x f16  (4 VGPRs)
typedef __attribute__((ext_vector_type(4))) _Float16 half4;   // 4 x f16  (2 VGPRs)
typedef __attribute__((ext_vector_type(4))) float f32x4;      // MFMA accumulator

// exp dispatch: fold log2e into Q scale and use raw v_exp_f32 when available
#if __has_builtin(__builtin_amdgcn_exp2f)
#define EXPX(x) __builtin_amdgcn_exp2f(x)
#define QSCALE (0.17677669529663688f * 1.4426950408889634f)
#else
#define EXPX(x) __expf(x)
#define QSCALE 0.17677669529663688f
#endif

// fp32 -> bf16 bits, round-to-nearest-even
__device__ __forceinline__ unsigned bfr(float x){
  unsigned u = __float_as_uint(x);
  return (u + 0x7FFFu + ((u >> 16) & 1u)) >> 16;
}
__device__ __forceinline__ unsigned pk2(float lo, float hi){   // bf16 pair [lo | hi<<16]
  return bfr(lo) | (bfr(hi) << 16);
}
__device__ __forceinline__ unsigned hpk(float a, float b){     // f16 pair
  _Float16 ha = (_Float16)a, hb = (_Float16)b;
  unsigned short ua = __builtin_bit_cast(unsigned short, ha);
  unsigned short ub = __builtin_bit_cast(unsigned short, hb);
  return (unsigned)ua | ((unsigned)ub << 16);
}
__device__ __forceinline__ half4 pk4rtz(float a, float b, float c, float d){ // 2x v_cvt_pkrtz
  auto lo = __builtin_amdgcn_cvt_pkrtz(a, b);
  auto hi = __builtin_amdgcn_cvt_pkrtz(c, d);
  uint2 u = make_uint2(__builtin_bit_cast(unsigned, lo), __builtin_bit_cast(unsigned, hi));
  return __builtin_bit_cast(half4, u);
}

// ---------------- Kernel 1: importance + fused x->out copy (float4-along-N gather) --------
// fp32 throughout (top-K selection must match fp32 reference ranking). See R17 notes.
__global__ __launch_bounds__(256) void imp_kernel(
    const float* __restrict__ x, const float* __restrict__ bmap,
    const float* __restrict__ w1, const float* __restrict__ b1,
    const float* __restrict__ w2, const float* __restrict__ b2,
    float* __restrict__ imp_out, float* __restrict__ outx)
{
  __shared__ float xs[256][32];   // 32KB, [channel][pixel], XOR-swizzled 16B granules
  __shared__ float red[4][32];
  const int t = threadIdx.x;
  const int b = blockIdx.x >> 7, tile = blockIdx.x & 127;
  const int n0 = tile * 32;
  { // gather + x->out copy: thread (p4=t&7 -> pixels 4p4..+3, co=t>>3 -> channel offset)
    const int p4 = t & 7, co = t >> 3;
    const float* xb = x + (size_t)b*C_*N_ + n0 + 4*p4;
    float* ox = outx + (size_t)b*C_*N_ + n0 + 4*p4;
    #pragma unroll
    for (int s = 0; s < 8; s++){
      const int c = s*32 + co;
      float4 v = *(const float4*)(xb + (size_t)c*N_);
      *(float4*)(ox + (size_t)c*N_) = v;
      *(float4*)&xs[c][4*(p4 ^ (c & 7))] = v;
    }
  }
  __syncthreads();
  const int pg = t & 7, og = t >> 3;   // pixels 4pg..+3, outs {og, og+32}
  float acc[4][2];
  #pragma unroll
  for (int pp=0;pp<4;pp++){ acc[pp][0]=0.f; acc[pp][1]=0.f; }
  #pragma unroll 2
  for (int c8 = 0; c8 < 256; c8 += 8){
    float4 xv[8];
    #pragma unroll
    for (int ci = 0; ci < 8; ci++){
      const int c = c8 + ci;
      xv[ci] = *(const float4*)&xs[c][4*(pg ^ (c & 7))];
    }
    #pragma unroll
    for (int oo = 0; oo < 2; oo++){
      const float* wr = w1 + (size_t)(og + 32*oo)*C_ + c8;
      float4 wa = *(const float4*)wr;
      float4 wb = *(const float4*)(wr+4);
      #pragma unroll
      for (int pp = 0; pp < 4; pp++){
        const float x0 = (&xv[0].x)[pp], x1 = (&xv[1].x)[pp];
        const float x2 = (&xv[2].x)[pp], x3 = (&xv[3].x)[pp];
        const float x4 = (&xv[4].x)[pp], x5 = (&xv[5].x)[pp];
        const float x6 = (&xv[6].x)[pp], x7 = (&xv[7].x)[pp];
        acc[pp][oo] += x0*wa.x + x1*wa.y + x2*wa.z + x3*wa.w
                     + x4*wb.x + x5*wb.y + x6*wb.z + x7*wb.w;
      }
    }
  }
  // epilogue: GELU + w2 dot, reduce over the 64 hidden outs
  float part[4] = {0.f,0.f,0.f,0.f};
  #pragma unroll
  for (int oo=0;oo<2;oo++){
    const int o = og + 32*oo;
    const float b1o = b1[o], w2o = w2[o];
    #pragma unroll
    for (int pp=0;pp<4;pp++){
      float a = acc[pp][oo] + b1o;
      float g = 0.5f*a*(1.f + erff(a*0.70710678118654752f));  // exact GELU
      part[pp] += w2o*g;
    }
  }
  #pragma unroll
  for (int pp=0;pp<4;pp++){
    part[pp] += __shfl_xor(part[pp], 8);    // sum over the wave's 8 og-subgroups
    part[pp] += __shfl_xor(part[pp], 16);
    part[pp] += __shfl_xor(part[pp], 32);
  }
  const int w = t >> 6;
  if ((t & 63) < 8){
    #pragma unroll
    for (int pp=0;pp<4;pp++) red[w][4*(t&7)+pp] = part[pp];
  }
  __syncthreads();
  if (t < 32){
    float s = red[0][t]+red[1][t]+red[2][t]+red[3][t] + b2[0];
    float sig = 1.f/(1.f+expf(-s));
    imp_out[(size_t)b*N_ + n0 + t] = sig + 0.5f*bmap[(size_t)b*N_ + n0 + t];
  }
}

// ---------------- Kernel 2: exact top-K via radix-select (+fused w2h conversion) ----------
__global__ __launch_bounds__(1024) void topk_kernel(
    const float* __restrict__ imp, int* __restrict__ tidx,
    const float* __restrict__ wq, const float* __restrict__ wk,
    const float* __restrict__ wv, const float* __restrict__ wo,
    unsigned short* __restrict__ wh)
{
  const int t = threadIdx.x;
  if (blockIdx.x >= 8){               // ---- fused w2h ----
    const int idx = blockIdx.x - 8;   // 0..31
    const int set = idx >> 3, chunk = idx & 7;
    const float* src = set==0 ? wq : set==1 ? wk : set==2 ? wv : wo;
    const int e = (chunk*1024 + t)*8;
    float4 a = *(const float4*)(src + e);
    float4 b = *(const float4*)(src + e + 4);
    uint4 o;
    o.x = hpk(a.x, a.y); o.y = hpk(a.z, a.w);
    o.z = hpk(b.x, b.y); o.w = hpk(b.z, b.w);
    *(uint4*)(wh + (size_t)set*65536 + e) = o;
    return;
  }
  // ---- radix-select top-K ----
  __shared__ unsigned hist[4096];
  __shared__ unsigned long long lst[4096];
  __shared__ unsigned wsum[16];
  __shared__ int scal[4];             // [0]=cnt, [1]=pivot, [2]=rank r
  const int b = blockIdx.x;
  const float* ib = imp + (size_t)b*N_;
  const int lane = t & 63, w = t >> 6;

  unsigned uu[4];
  #pragma unroll
  for (int u2 = 0; u2 < 4; u2++){
    unsigned u = __float_as_uint(ib[4*t + u2]);
    uu[u2] = (u & 0x80000000u) ? ~u : (u | 0x80000000u);   // order-preserving bits
  }
  hist[t] = 0; hist[t+1024] = 0; hist[t+2048] = 0; hist[t+3072] = 0;
  if (t == 0) scal[0] = 0;
  __syncthreads();
  #pragma unroll
  for (int u2 = 0; u2 < 4; u2++) atomicAdd(&hist[uu[u2] >> 20], 1u);
  __syncthreads();
  // descending suffix counts: thread owns buckets 4t..4t+3 (ascending bucket order)
  const unsigned h0 = hist[4*t], h1 = hist[4*t+1], h2 = hist[4*t+2], h3 = hist[4*t+3];
  const unsigned s4 = h0 + h1 + h2 + h3;
  unsigned sfx = s4;                   // sum over lanes >= this lane (within wave)
  #pragma unroll
  for (int d = 1; d < 64; d <<= 1){
    unsigned v = __shfl_down(sfx, d);
    if (lane + d < 64) sfx += v;
  }
  if (lane == 0) wsum[w] = sfx;
  __syncthreads();
  unsigned Wt = 0;
  #pragma unroll
  for (int ww = 0; ww < 16; ww++) if (ww > w) Wt += wsum[ww];
  const unsigned G3 = Wt + (sfx - s4);  // count strictly greater than bucket 4t+3
  const unsigned G2 = G3 + h3, G1 = G2 + h2, G0 = G1 + h1;
  if (G0 < 1024u && G0 + h0 >= 1024u){ scal[1] = 4*t+0; scal[2] = 1024 - (int)G0; }
  if (G1 < 1024u && G1 + h1 >= 1024u){ scal[1] = 4*t+1; scal[2] = 1024 - (int)G1; }
  if (G2 < 1024u && G2 + h2 >= 1024u){ scal[1] = 4*t+2; scal[2] = 1024 - (int)G2; }
  if (G3 < 1024u && G3 + h3 >= 1024u){ scal[1] = 4*t+3; scal[2] = 1024 - (int)G3; }
  __syncthreads();
  const unsigned p = (unsigned)scal[1];
  const int r = scal[2];
  // gather pivot-bucket elements (full 64-bit keys)
  #pragma unroll
  for (int u2 = 0; u2 < 4; u2++){
    if ((uu[u2] >> 20) == p){
      int pos = atomicAdd(&scal[0], 1);
      lst[pos] = ((unsigned long long)uu[u2] << 32) | (unsigned)(~(4*t + u2));
    }
  }
  __syncthreads();
  const int cnt = scal[0];
  int pad = 1; while (pad < cnt) pad <<= 1;
  for (int m = t; m < pad; m += 1024) if (m >= cnt) lst[m] = 0ull;  // pad = smallest
  __syncthreads();
  for (int k = 2; k <= pad; k <<= 1){
    for (int j = k >> 1; j > 0; j >>= 1){
      for (int m = t; m < (pad >> 1); m += 1024){
        int i = 2*m - (m & (j-1));
        int l = i + j;
        unsigned long long a = lst[i], c = lst[l];
        if ((a > c) == ((i & k) == 0)){ lst[i] = c; lst[l] = a; }
      }
      __syncthreads();
    }
  }
  const unsigned long long thr = lst[pad - r];   // r-th largest in pivot bucket
  // ordered compaction: key64 >= thr <=> in top-1024 (keys distinct)
  __shared__ int ws2[16];
  int sel[4]; int cnt2 = 0;
  #pragma unroll
  for (int u2 = 0; u2 < 4; u2++){
    const int m = 4*t + u2;
    unsigned long long key = ((unsigned long long)uu[u2] << 32) | (unsigned)(~m);
    sel[u2] = (key >= thr) ? 1 : 0;
    cnt2 += sel[u2];
  }
  int incl = cnt2;
  #pragma unroll
  for (int d2 = 1; d2 < 64; d2 <<= 1){
    int v2 = __shfl_up(incl, d2);
    if (lane >= d2) incl += v2;
  }
  if (lane == 63) ws2[w] = incl;
  __syncthreads();
  int base = 0;
  #pragma unroll
  for (int ww = 0; ww < 16; ww++) if (ww < w) base += ws2[ww];
  int pos = base + incl - cnt2;
  #pragma unroll
  for (int u2 = 0; u2 < 4; u2++){
    if (sel[u2]) tidx[(size_t)b*K_ + pos++] = 4*t + u2;
  }
}

// ---------------- Kernel 3: fused gather + Q/K/V projections via f16 MFMA ----------------
// Q is pre-scaled by QSCALE. V^T stored f16 with keys PERMUTED within each 32-token block:
//   rel key k (0..31) -> pos 8*((k&15)>>2) + 4*((k>>4)&1) + (k&3)
__global__ __launch_bounds__(512) void qkv_kernel(
    const float* __restrict__ x, const int* __restrict__ tidx,
    const unsigned short* __restrict__ wh,
    const float* __restrict__ bq, const float* __restrict__ bk, const float* __restrict__ bv,
    float* __restrict__ xsp, unsigned short* __restrict__ qbf,
    unsigned short* __restrict__ kbf, unsigned short* __restrict__ vtb)
{
  __shared__ unsigned short xsb[16][256];   // f16 bits, swizzled 16B granules
  const int t = threadIdx.x;
  const int kt = blockIdx.x, b = blockIdx.y;
  const int tok0 = kt*16;
  { // gather: thread t -> token i = t&15, granule jg = t>>4 (8 channels)
    const int i = t & 15, jg = t >> 4;
    const int n = tidx[(size_t)b*K_ + tok0 + i];
    const float* xb = x + (size_t)b*C_*N_ + n;
    float v[8];
    #pragma unroll
    for (int u = 0; u < 8; u++) v[u] = xb[(size_t)(jg*8+u)*N_];
    float* xr = xsp + ((size_t)b*K_ + tok0 + i)*C_ + jg*8;
    *(float4*)(xr)     = make_float4(v[0],v[1],v[2],v[3]);
    *(float4*)(xr + 4) = make_float4(v[4],v[5],v[6],v[7]);
    uint4 pw;
    pw.x = hpk(v[0],v[1]); pw.y = hpk(v[2],v[3]);
    pw.z = hpk(v[4],v[5]); pw.w = hpk(v[6],v[7]);
    *(uint4*)((char*)&xsb[0][0] + i*512 + ((jg ^ (i&7))*16)) = pw;
  }
  __syncthreads();

  const int lane = t & 63, w = t >> 6;
  const int g = lane >> 4, c = lane & 15;

  f32x4 acc[3][2];
  #pragma unroll
  for (int s=0;s<3;s++)
    #pragma unroll
    for (int j=0;j<2;j++) acc[s][j] = (f32x4){0.f,0.f,0.f,0.f};

  #pragma unroll 1
  for (int ks = 0; ks < 8; ks++){
    half8 Xf = *(const half8*)((const char*)&xsb[0][0] + c*512 + (((4*ks+g) ^ (c&7))*16));
    half8 Wf[3][2];
    #pragma unroll
    for (int s=0;s<3;s++)
      #pragma unroll
      for (int j=0;j<2;j++)
        Wf[s][j] = *(const half8*)(wh + (size_t)s*65536 + (32*w + 16*j + c)*C_ + ks*32 + 8*g);
    acc[0][0] = __builtin_amdgcn_mfma_f32_16x16x32_f16(Wf[0][0], Xf, acc[0][0], 0,0,0);
    acc[0][1] = __builtin_amdgcn_mfma_f32_16x16x32_f16(Wf[0][1], Xf, acc[0][1], 0,0,0);
    acc[1][0] = __builtin_amdgcn_mfma_f32_16x16x32_f16(Wf[1][0], Xf, acc[1][0], 0,0,0);
    acc[1][1] = __builtin_amdgcn_mfma_f32_16x16x32_f16(Wf[1][1], Xf, acc[1][1], 0,0,0);
    acc[2][0] = __builtin_amdgcn_mfma_f32_16x16x32_f16(Xf, Wf[2][0], acc[2][0], 0,0,0);
    acc[2][1] = __builtin_amdgcn_mfma_f32_16x16x32_f16(Xf, Wf[2][1], acc[2][1], 0,0,0);
  }

  const int bh = b*NH_ + w;   // head = wave index
  #pragma unroll
  for (int s=0;s<2;s++){
    const float* bias = s ? bk : bq;
    const float sc = s ? 1.f : QSCALE;
    unsigned short* dstb = s ? kbf : qbf;
    #pragma unroll
    for (int j=0;j<2;j++){
      f32x4 a = acc[s][j];
      float4 bb = *(const float4*)(bias + w*32 + 16*j + 4*g);
      unsigned lo = pk2((a[0]+bb.x)*sc, (a[1]+bb.y)*sc);
      unsigned hi = pk2((a[2]+bb.z)*sc, (a[3]+bb.w)*sc);
      unsigned short* dst = dstb + ((size_t)bh*K_ + tok0 + c)*HD_ + 16*j + 4*g;
      *(uint2*)dst = make_uint2(lo, hi);
    }
  }
  // V^T scatter, f16, key-permuted: lane holds tokens tok0+4g+{0..3} = rel 16*half+4g+r
  const int base32 = tok0 & ~31;
  const int half   = (tok0 >> 4) & 1;
  #pragma unroll
  for (int j=0;j<2;j++){
    f32x4 a = acc[2][j];
    const float bvv = bv[w*32 + 16*j + c];
    unsigned lo = hpk(a[0]+bvv, a[1]+bvv);
    unsigned hi = hpk(a[2]+bvv, a[3]+bvv);
    unsigned short* dst = vtb + ((size_t)bh*HD_ + 16*j + c)*K_ + base32 + 8*g + 4*half;
    *(uint2*)dst = make_uint2(lo, hi);
  }
}

// ---------------- Kernel 4: MFMA flash attention, depth-4 register pipeline ----------------
// Loads for chunk i+4 issued right after chunk i is consumed: ~3 compute-steps (~700 cyc)
// of latency cover vs the old depth-2's ~1 step (~240 cyc) — the measured exposed-latency fix.
// L computed on the matrix pipe: mfma(ONES, P) gives every lane Sum_k P[k][q].
// Grid flat = h + 8*(qt + 8*b). 8 waves = (sp,qq): split-K 2-way, merge by plain addition.
__global__ __launch_bounds__(512) void attn_kernel(
    const unsigned short* __restrict__ qbf, const unsigned short* __restrict__ kbf,
    const unsigned short* __restrict__ vtb, unsigned short* __restrict__ ob)
{
  __shared__ float po[4][64][19];   // [qq][lane][ot(16) | L0 | L1]; stride 19 -> <=2-way
  const int tid = threadIdx.x;
  const int t = tid & 63, w = tid >> 6;
  const int sp = w >> 2, qq = w & 3;
  const int flat = blockIdx.x;
  const int h = flat & 7;
  const int rest = flat >> 3;      // 0..63
  const int qt = rest & 7;
  const int b = rest >> 3;         // 0..7
  const int g = t >> 4, c = t & 15;
  const int bh = b*NH_ + h;
  const int q0 = qt*128 + qq*32;   // 32 q-rows per wave

  short8 Qf0 = *(const short8*)(qbf + ((size_t)bh*K_ + q0 + c)*HD_ + g*8);
  short8 Qf1 = *(const short8*)(qbf + ((size_t)bh*K_ + q0 + 16 + c)*HD_ + g*8);

  const int kbeg = sp*512;
  const unsigned short* kp  = kbf + (size_t)bh*K_*HD_ + (size_t)(kbeg + c)*HD_ + g*8;
  const unsigned short* vp0 = vtb + ((size_t)bh*HD_ + c)*K_ + kbeg + g*8;
  const unsigned short* vp1 = vp0 + (size_t)16*K_;

  const half4 ONES = {(_Float16)1.f, (_Float16)1.f, (_Float16)1.f, (_Float16)1.f};
  f32x4 ot00 = {0.f,0.f,0.f,0.f}, ot01 = {0.f,0.f,0.f,0.f};  // qi=0: dv 0..15, 16..31
  f32x4 ot10 = {0.f,0.f,0.f,0.f}, ot11 = {0.f,0.f,0.f,0.f};  // qi=1
  f32x4 otL0 = {0.f,0.f,0.f,0.f}, otL1 = {0.f,0.f,0.f,0.f};  // L accumulators

#define ATTN_STEP(K0c,K1c,V0c,V1c) do {                                           \
    f32x4 z = {0.f,0.f,0.f,0.f};                                                  \
    __builtin_amdgcn_s_setprio(1);                                                \
    f32x4 s00 = __builtin_amdgcn_mfma_f32_16x16x32_bf16(K0c, Qf0, z, 0, 0, 0);    \
    f32x4 s01 = __builtin_amdgcn_mfma_f32_16x16x32_bf16(K1c, Qf0, z, 0, 0, 0);    \
    f32x4 s10 = __builtin_amdgcn_mfma_f32_16x16x32_bf16(K0c, Qf1, z, 0, 0, 0);    \
    f32x4 s11 = __builtin_amdgcn_mfma_f32_16x16x32_bf16(K1c, Qf1, z, 0, 0, 0);    \
    __builtin_amdgcn_s_setprio(0);                                                \
    float p00[4], p01[4], p10[4], p11[4];                                         \
    _Pragma("unroll")                                                             \
    for (int r=0;r<4;r++){                                                        \
      p00[r] = EXPX(s00[r]); p01[r] = EXPX(s01[r]);                               \
      p10[r] = EXPX(s10[r]); p11[r] = EXPX(s11[r]);                               \
    }                                                                             \
    half4 P00 = pk4rtz(p00[0], p00[1], p00[2], p00[3]);                           \
    half4 P01 = pk4rtz(p01[0], p01[1], p01[2], p01[3]);                           \
    half4 P10 = pk4rtz(p10[0], p10[1], p10[2], p10[3]);                           \
    half4 P11 = pk4rtz(p11[0], p11[1], p11[2], p11[3]);                           \
    half4 A0lo = __builtin_shufflevector(V0c, V0c, 0, 1, 2, 3);                   \
    half4 A0hi = __builtin_shufflevector(V0c, V0c, 4, 5, 6, 7);                   \
    half4 A1lo = __builtin_shufflevector(V1c, V1c, 0, 1, 2, 3);                   \
    half4 A1hi = __builtin_shufflevector(V1c, V1c, 4, 5, 6, 7);                   \
    __builtin_amdgcn_s_setprio(1);                                                \
    ot00 = __builtin_amdgcn_mfma_f32_16x16x16f16(A0lo, P00, ot00, 0, 0, 0);       \
    ot00 = __builtin_amdgcn_mfma_f32_16x16x16f16(A0hi, P01, ot00, 0, 0, 0);       \
    ot01 = __builtin_amdgcn_mfma_f32_16x16x16f16(A1lo, P00, ot01, 0, 0, 0);       \
    ot01 = __builtin_amdgcn_mfma_f32_16x16x16f16(A1hi, P01, ot01, 0, 0, 0);       \
    ot10 = __builtin_amdgcn_mfma_f32_16x16x16f16(A0lo, P10, ot10, 0, 0, 0);       \
    ot10 = __builtin_amdgcn_mfma_f32_16x16x16f16(A0hi, P11, ot10, 0, 0, 0);       \
    ot11 = __builtin_amdgcn_mfma_f32_16x16x16f16(A1lo, P10, ot11, 0, 0, 0);       \
    ot11 = __builtin_amdgcn_mfma_f32_16x16x16f16(A1hi, P11, ot11, 0, 0, 0);       \
    otL0 = __builtin_amdgcn_mfma_f32_16x16x16f16(ONES, P00, otL0, 0, 0, 0);       \
    otL0 = __builtin_amdgcn_mfma_f32_16x16x16f16(ONES, P01, otL0, 0, 0, 0);       \
    otL1 = __builtin_amdgcn_mfma_f32_16x16x16f16(ONES, P10, otL1, 0, 0, 0);       \
    otL1 = __builtin_amdgcn_mfma_f32_16x16x16f16(ONES, P11, otL1, 0, 0, 0);       \
    __builtin_amdgcn_s_setprio(0);                                                \
  } while(0)

#define LOADSET(Kx0,Kx1,Vx0,Vx1) do {                                             \
    Kx0 = *(const short8*)(kp);                                                   \
    Kx1 = *(const short8*)(kp + 16*HD_);                                          \
    Vx0 = *(const half8*)(vp0);                                                   \
    Vx1 = *(const half8*)(vp1);                                                   \
  } while(0)
#define ADV do { kp += 32*HD_; vp0 += 32; vp1 += 32; } while(0)

  // depth-4 register pipeline: prologue loads chunks 0..3
  short8 K0a,K1a,K0b,K1b,K0c_,K1c_,K0d,K1d;
  half8  V0a,V1a,V0b,V1b,V0c_,V1c_,V0d,V1d;
  LOADSET(K0a,K1a,V0a,V1a); ADV;
  LOADSET(K0b,K1b,V0b,V1b); ADV;
  LOADSET(K0c_,K1c_,V0c_,V1c_); ADV;
  LOADSET(K0d,K1d,V0d,V1d);

  // steady state: consume set, immediately re-issue its loads for chunk it+4
  // (tail prefetches read <=8KB past this (b,h) region into adjacent allocated ws)
  for (int it = 0; it < 16; it += 4){
    ADV;
    ATTN_STEP(K0a, K1a, V0a, V1a);
    LOADSET(K0a,K1a,V0a,V1a);
    ADV;
    ATTN_STEP(K0b, K1b, V0b, V1b);
    LOADSET(K0b,K1b,V0b,V1b);
    ADV;
    ATTN_STEP(K0c_, K1c_, V0c_, V1c_);
    LOADSET(K0c_,K1c_,V0c_,V1c_);
    ADV;
    ATTN_STEP(K0d, K1d, V0d, V1d);
    LOADSET(K0d,K1d,V0d,V1d);
  }
#undef ATTN_STEP
#undef LOADSET
#undef ADV

  if (sp == 1){
    float* d = po[qq][t];
    d[0]=ot00[0]; d[1]=ot00[1]; d[2]=ot00[2];  d[3]=ot00[3];
    d[4]=ot01[0]; d[5]=ot01[1]; d[6]=ot01[2];  d[7]=ot01[3];
    d[8]=ot10[0]; d[9]=ot10[1]; d[10]=ot10[2]; d[11]=ot10[3];
    d[12]=ot11[0];d[13]=ot11[1];d[14]=ot11[2]; d[15]=ot11[3];
    d[16]=otL0[0]; d[17]=otL1[0];
  }
  __syncthreads();
  if (sp == 0){
    const float* d = po[qq][t];
    ot00[0]+=d[0]; ot00[1]+=d[1]; ot00[2]+=d[2];  ot00[3]+=d[3];
    ot01[0]+=d[4]; ot01[1]+=d[5]; ot01[2]+=d[6];  ot01[3]+=d[7];
    ot10[0]+=d[8]; ot10[1]+=d[9]; ot10[2]+=d[10]; ot10[3]+=d[11];
    ot11[0]+=d[12];ot11[1]+=d[13];ot11[2]+=d[14]; ot11[3]+=d[15];
    const float L0 = otL0[0] + d[16];
    const float L1 = otL1[0] + d[17];
    const float i0 = 1.f / L0, i1 = 1.f / L1;
    unsigned short* o0 = ob + ((size_t)b*K_ + q0 + c)*C_ + h*HD_;
    unsigned short* o1 = ob + ((size_t)b*K_ + q0 + 16 + c)*C_ + h*HD_;
    *(uint2*)(o0 + 4*g)      = make_uint2(hpk(ot00[0]*i0, ot00[1]*i0), hpk(ot00[2]*i0, ot00[3]*i0));
    *(uint2*)(o0 + 16 + 4*g) = make_uint2(hpk(ot01[0]*i0, ot01[1]*i0), hpk(ot01[2]*i0, ot01[3]*i0));
    *(uint2*)(o1 + 4*g)      = make_uint2(hpk(ot10[0]*i1, ot10[1]*i1), hpk(ot10[2]*i1, ot10[3]*i1));
    *(uint2*)(o1 + 16 + 4*g) = make_uint2(hpk(ot11[0]*i1, ot11[1]*i1), hpk(ot11[2]*i1, ot11[3]*i1));
  }
}

// ---------------- Kernel 5: out-proj (f16 MFMA) + residual + LayerNorm + scatter ----------------
// 16-token tiles -> grid (64,8) = 512 blocks (2 per CU).
__global__ __launch_bounds__(512) void out_kernel(
    const unsigned short* __restrict__ ob, const float* __restrict__ xsp,
    const int* __restrict__ tidx, const unsigned short* __restrict__ woh, const float* __restrict__ bo,
    const float* __restrict__ lng, const float* __restrict__ lnb,
    float* __restrict__ out)
{
  __shared__ float red1[8][16], red2[8][16];
  __shared__ float mus[16], rss[16];
  __shared__ int nn[16];
  const int t = threadIdx.x;
  const int kt = blockIdx.x, b = blockIdx.y;
  const int tok0 = kt*16;
  const int lane = t & 63, w = t >> 6;
  const int g = lane >> 4, c = lane & 15;

  if (t < 16) nn[t] = tidx[(size_t)b*K_ + tok0 + t];

  f32x4 acc0 = {0.f,0.f,0.f,0.f}, acc1 = {0.f,0.f,0.f,0.f};

  const unsigned short* ob0 = ob + ((size_t)b*K_ + tok0)*C_;
  const unsigned short* wr0 = woh + (32*w + c)*C_;

  #pragma unroll 1
  for (int ks = 0; ks < 8; ks++){
    half8 Wf0 = *(const half8*)(wr0 + ks*32 + 8*g);
    half8 Wf1 = *(const half8*)(wr0 + 16*C_ + ks*32 + 8*g);
    half8 Of  = *(const half8*)(ob0 + (size_t)c*C_ + ks*32 + 8*g);
    acc0 = __builtin_amdgcn_mfma_f32_16x16x32_f16(Wf0, Of, acc0, 0,0,0);
    acc1 = __builtin_amdgcn_mfma_f32_16x16x32_f16(Wf1, Of, acc1, 0,0,0);
  }

  // bias + residual (fp32)
  const float* xr = xsp + ((size_t)b*K_ + tok0 + c)*C_ + 32*w + 4*g;
  {
    float4 bb0 = *(const float4*)(bo + 32*w + 4*g);
    float4 bb1 = *(const float4*)(bo + 32*w + 16 + 4*g);
    float4 xv0 = *(const float4*)(xr);
    float4 xv1 = *(const float4*)(xr + 16);
    acc0[0] += bb0.x + xv0.x; acc0[1] += bb0.y + xv0.y;
    acc0[2] += bb0.z + xv0.z; acc0[3] += bb0.w + xv0.w;
    acc1[0] += bb1.x + xv1.x; acc1[1] += bb1.y + xv1.y;
    acc1[2] += bb1.z + xv1.z; acc1[3] += bb1.w + xv1.w;
  }

  // LN partials: per token sum over this wave's 32 oc; g-groups share the token
  {
    float s1 = 0.f, s2 = 0.f;
    #pragma unroll
    for (int r=0;r<4;r++){ float y = acc0[r]; s1 += y; s2 += y*y; }
    #pragma unroll
    for (int r=0;r<4;r++){ float y = acc1[r]; s1 += y; s2 += y*y; }
    s1 += __shfl_xor(s1, 16); s2 += __shfl_xor(s2, 16);
    s1 += __shfl_xor(s1, 32); s2 += __shfl_xor(s2, 32);
    if (g == 0){ red1[w][c] = s1; red2[w][c] = s2; }
  }
  __syncthreads();
  if (t < 16){
    float a = 0.f, q2 = 0.f;
    #pragma unroll
    for (int ww=0;ww<8;ww++){ a += red1[ww][t]; q2 += red2[ww][t]; }
    float mu = a*(1.f/256.f);
    float var = q2*(1.f/256.f) - mu*mu;
    mus[t] = mu;
    rss[t] = rsqrtf(var + 1e-5f);
  }
  __syncthreads();

  // scale/shift + scatter
  const float mu = mus[c], rs = rss[c];
  const int n = nn[c];
  float* outb = out + (size_t)b*C_*N_;
  #pragma unroll
  for (int j=0;j<2;j++){
    const int oc0 = 32*w + 16*j + 4*g;
    float4 gvv = *(const float4*)(lng + oc0);
    float4 bvv = *(const float4*)(lnb + oc0);
    const f32x4& a = j ? acc1 : acc0;
    outb[(size_t)(oc0+0)*N_ + n] = (a[0]-mu)*rs*gvv.x + bvv.x;
    outb[(size_t)(oc0+1)*N_ + n] = (a[1]-mu)*rs*gvv.y + bvv.y;
    outb[(size_t)(oc0+2)*N_ + n] = (a[2]-mu)*rs*gvv.z + bvv.z;
    outb[(size_t)(oc0+3)*N_ + n] = (a[3]-mu)*rs*gvv.w + bvv.w;
  }
}

extern "C" void kernel_launch(void* const* d_in, const int* in_sizes, int n_in,
                              void* d_out, int out_size, void* d_ws, size_t ws_size,
                              hipStream_t stream)
{
  const float* x    = (const float*)d_in[0];
  const float* bmap = (const float*)d_in[1];
  const float* w1   = (const float*)d_in[2];
  const float* b1   = (const float*)d_in[3];
  const float* w2   = (const float*)d_in[4];
  const float* b2   = (const float*)d_in[5];
  const float* wq   = (const float*)d_in[6];
  const float* bq   = (const float*)d_in[7];
  const float* wk   = (const float*)d_in[8];
  const float* bk   = (const float*)d_in[9];
  const float* wv   = (const float*)d_in[10];
  const float* bv   = (const float*)d_in[11];
  const float* wo   = (const float*)d_in[12];
  const float* bo   = (const float*)d_in[13];
  const float* lng  = (const float*)d_in[14];
  const float* lnb  = (const float*)d_in[15];

  float* out = (float*)d_out;
  float* imp_out = out + (size_t)B_*C_*N_;   // importance is output #2, concatenated

  char* wsb = (char*)d_ws;
  int*   tidx = (int*)wsb;                                // 64 KB slot
  float* xsp  = (float*)(wsb + 65536);                    // [B,K,C] fp32, 8 MB
  unsigned short* ob16 = (unsigned short*)(xsp + (size_t)B_*K_*C_); // [B,K,C] f16, 4 MB (8 MB slot)
  unsigned short* qbf = ob16 + 2*(size_t)B_*K_*C_;        // [B,H,K,32] bf16, 4 MB
  unsigned short* kbf = qbf + (size_t)B_*NH_*K_*HD_;      // [B,H,K,32] bf16, 4 MB
  unsigned short* vtb = kbf + (size_t)B_*NH_*K_*HD_;      // [B,H,32,K] f16 key-permuted, 4 MB
  unsigned short* wh  = vtb + (size_t)B_*NH_*K_*HD_;      // [4][256][256] f16, 512 KB

  imp_kernel <<<dim3(1024),     dim3(256),  0, stream>>>(x, bmap, w1, b1, w2, b2, imp_out, out);
  topk_kernel<<<dim3(40),       dim3(1024), 0, stream>>>(imp_out, tidx, wq, wk, wv, wo, wh);
  qkv_kernel <<<dim3(64, 8),    dim3(512),  0, stream>>>(x, tidx, wh, bq, bk, bv, xsp, qbf, kbf, vtb);
  attn_kernel<<<dim3(512),      dim3(512),  0, stream>>>(qbf, kbf, vtb, ob16);
  out_kernel <<<dim3(64, 8),    dim3(512),  0, stream>>>(ob16, xsp, tidx, wh + 3*65536, bo, lng, lnb, out);
}

// Round 20
// 128.829 us; speedup vs baseline: 1.0184x; 1.0184x over previous
//
#include <hip/hip_runtime.h>
#include <math.h>

#define B_ 8
#define C_ 256
#define N_ 4096
#define K_ 1024
#define NH_ 8
#define HD_ 32

typedef __attribute__((ext_vector_type(8))) short short8;     // 8 x bf16 (4 VGPRs)
typedef __attribute__((ext_vector_type(8))) _Float16 half8;   // 8 x f16  (4 VGPRs)
typedef __attribute__((ext_vector_type(4))) _Float16 half4;   // 4 x f16  (2 VGPRs)
typedef __attribute__((ext_vector_type(4))) float f32x4;      // MFMA accumulator

// exp dispatch: fold log2e into Q scale and use raw v_exp_f32 when available
#if __has_builtin(__builtin_amdgcn_exp2f)
#define EXPX(x) __builtin_amdgcn_exp2f(x)
#define QSCALE (0.17677669529663688f * 1.4426950408889634f)
#else
#define EXPX(x) __expf(x)
#define QSCALE 0.17677669529663688f
#endif

// fp32 -> bf16 bits, round-to-nearest-even
__device__ __forceinline__ unsigned bfr(float x){
  unsigned u = __float_as_uint(x);
  return (u + 0x7FFFu + ((u >> 16) & 1u)) >> 16;
}
__device__ __forceinline__ unsigned pk2(float lo, float hi){   // bf16 pair [lo | hi<<16]
  return bfr(lo) | (bfr(hi) << 16);
}
__device__ __forceinline__ unsigned hpk(float a, float b){     // f16 pair
  _Float16 ha = (_Float16)a, hb = (_Float16)b;
  unsigned short ua = __builtin_bit_cast(unsigned short, ha);
  unsigned short ub = __builtin_bit_cast(unsigned short, hb);
  return (unsigned)ua | ((unsigned)ub << 16);
}
__device__ __forceinline__ half4 pk4rtz(float a, float b, float c, float d){ // 2x v_cvt_pkrtz
  auto lo = __builtin_amdgcn_cvt_pkrtz(a, b);
  auto hi = __builtin_amdgcn_cvt_pkrtz(c, d);
  uint2 u = make_uint2(__builtin_bit_cast(unsigned, lo), __builtin_bit_cast(unsigned, hi));
  return __builtin_bit_cast(half4, u);
}

// ---------------- Kernel 1: importance + fused x->out copy (float4-along-N gather) --------
// fp32 throughout (top-K selection must match fp32 reference ranking). See R17 notes.
__global__ __launch_bounds__(256) void imp_kernel(
    const float* __restrict__ x, const float* __restrict__ bmap,
    const float* __restrict__ w1, const float* __restrict__ b1,
    const float* __restrict__ w2, const float* __restrict__ b2,
    float* __restrict__ imp_out, float* __restrict__ outx)
{
  __shared__ float xs[256][32];   // 32KB, [channel][pixel], XOR-swizzled 16B granules
  __shared__ float red[4][32];
  const int t = threadIdx.x;
  const int b = blockIdx.x >> 7, tile = blockIdx.x & 127;
  const int n0 = tile * 32;
  { // gather + x->out copy: thread (p4=t&7 -> pixels 4p4..+3, co=t>>3 -> channel offset)
    const int p4 = t & 7, co = t >> 3;
    const float* xb = x + (size_t)b*C_*N_ + n0 + 4*p4;
    float* ox = outx + (size_t)b*C_*N_ + n0 + 4*p4;
    #pragma unroll
    for (int s = 0; s < 8; s++){
      const int c = s*32 + co;
      float4 v = *(const float4*)(xb + (size_t)c*N_);
      *(float4*)(ox + (size_t)c*N_) = v;
      *(float4*)&xs[c][4*(p4 ^ (c & 7))] = v;
    }
  }
  __syncthreads();
  const int pg = t & 7, og = t >> 3;   // pixels 4pg..+3, outs {og, og+32}
  float acc[4][2];
  #pragma unroll
  for (int pp=0;pp<4;pp++){ acc[pp][0]=0.f; acc[pp][1]=0.f; }
  #pragma unroll 2
  for (int c8 = 0; c8 < 256; c8 += 8){
    float4 xv[8];
    #pragma unroll
    for (int ci = 0; ci < 8; ci++){
      const int c = c8 + ci;
      xv[ci] = *(const float4*)&xs[c][4*(pg ^ (c & 7))];
    }
    #pragma unroll
    for (int oo = 0; oo < 2; oo++){
      const float* wr = w1 + (size_t)(og + 32*oo)*C_ + c8;
      float4 wa = *(const float4*)wr;
      float4 wb = *(const float4*)(wr+4);
      #pragma unroll
      for (int pp = 0; pp < 4; pp++){
        const float x0 = (&xv[0].x)[pp], x1 = (&xv[1].x)[pp];
        const float x2 = (&xv[2].x)[pp], x3 = (&xv[3].x)[pp];
        const float x4 = (&xv[4].x)[pp], x5 = (&xv[5].x)[pp];
        const float x6 = (&xv[6].x)[pp], x7 = (&xv[7].x)[pp];
        acc[pp][oo] += x0*wa.x + x1*wa.y + x2*wa.z + x3*wa.w
                     + x4*wb.x + x5*wb.y + x6*wb.z + x7*wb.w;
      }
    }
  }
  // epilogue: GELU + w2 dot, reduce over the 64 hidden outs
  float part[4] = {0.f,0.f,0.f,0.f};
  #pragma unroll
  for (int oo=0;oo<2;oo++){
    const int o = og + 32*oo;
    const float b1o = b1[o], w2o = w2[o];
    #pragma unroll
    for (int pp=0;pp<4;pp++){
      float a = acc[pp][oo] + b1o;
      float g = 0.5f*a*(1.f + erff(a*0.70710678118654752f));  // exact GELU
      part[pp] += w2o*g;
    }
  }
  #pragma unroll
  for (int pp=0;pp<4;pp++){
    part[pp] += __shfl_xor(part[pp], 8);    // sum over the wave's 8 og-subgroups
    part[pp] += __shfl_xor(part[pp], 16);
    part[pp] += __shfl_xor(part[pp], 32);
  }
  const int w = t >> 6;
  if ((t & 63) < 8){
    #pragma unroll
    for (int pp=0;pp<4;pp++) red[w][4*(t&7)+pp] = part[pp];
  }
  __syncthreads();
  if (t < 32){
    float s = red[0][t]+red[1][t]+red[2][t]+red[3][t] + b2[0];
    float sig = 1.f/(1.f+expf(-s));
    imp_out[(size_t)b*N_ + n0 + t] = sig + 0.5f*bmap[(size_t)b*N_ + n0 + t];
  }
}

// ---------------- Kernel 2: exact top-K via radix-select (+fused w2h conversion) ----------
__global__ __launch_bounds__(1024) void topk_kernel(
    const float* __restrict__ imp, int* __restrict__ tidx,
    const float* __restrict__ wq, const float* __restrict__ wk,
    const float* __restrict__ wv, const float* __restrict__ wo,
    unsigned short* __restrict__ wh)
{
  const int t = threadIdx.x;
  if (blockIdx.x >= 8){               // ---- fused w2h ----
    const int idx = blockIdx.x - 8;   // 0..31
    const int set = idx >> 3, chunk = idx & 7;
    const float* src = set==0 ? wq : set==1 ? wk : set==2 ? wv : wo;
    const int e = (chunk*1024 + t)*8;
    float4 a = *(const float4*)(src + e);
    float4 b = *(const float4*)(src + e + 4);
    uint4 o;
    o.x = hpk(a.x, a.y); o.y = hpk(a.z, a.w);
    o.z = hpk(b.x, b.y); o.w = hpk(b.z, b.w);
    *(uint4*)(wh + (size_t)set*65536 + e) = o;
    return;
  }
  // ---- radix-select top-K ----
  __shared__ unsigned hist[4096];
  __shared__ unsigned long long lst[4096];
  __shared__ unsigned wsum[16];
  __shared__ int scal[4];             // [0]=cnt, [1]=pivot, [2]=rank r
  const int b = blockIdx.x;
  const float* ib = imp + (size_t)b*N_;
  const int lane = t & 63, w = t >> 6;

  unsigned uu[4];
  #pragma unroll
  for (int u2 = 0; u2 < 4; u2++){
    unsigned u = __float_as_uint(ib[4*t + u2]);
    uu[u2] = (u & 0x80000000u) ? ~u : (u | 0x80000000u);   // order-preserving bits
  }
  hist[t] = 0; hist[t+1024] = 0; hist[t+2048] = 0; hist[t+3072] = 0;
  if (t == 0) scal[0] = 0;
  __syncthreads();
  #pragma unroll
  for (int u2 = 0; u2 < 4; u2++) atomicAdd(&hist[uu[u2] >> 20], 1u);
  __syncthreads();
  // descending suffix counts: thread owns buckets 4t..4t+3 (ascending bucket order)
  const unsigned h0 = hist[4*t], h1 = hist[4*t+1], h2 = hist[4*t+2], h3 = hist[4*t+3];
  const unsigned s4 = h0 + h1 + h2 + h3;
  unsigned sfx = s4;                   // sum over lanes >= this lane (within wave)
  #pragma unroll
  for (int d = 1; d < 64; d <<= 1){
    unsigned v = __shfl_down(sfx, d);
    if (lane + d < 64) sfx += v;
  }
  if (lane == 0) wsum[w] = sfx;
  __syncthreads();
  unsigned Wt = 0;
  #pragma unroll
  for (int ww = 0; ww < 16; ww++) if (ww > w) Wt += wsum[ww];
  const unsigned G3 = Wt + (sfx - s4);  // count strictly greater than bucket 4t+3
  const unsigned G2 = G3 + h3, G1 = G2 + h2, G0 = G1 + h1;
  if (G0 < 1024u && G0 + h0 >= 1024u){ scal[1] = 4*t+0; scal[2] = 1024 - (int)G0; }
  if (G1 < 1024u && G1 + h1 >= 1024u){ scal[1] = 4*t+1; scal[2] = 1024 - (int)G1; }
  if (G2 < 1024u && G2 + h2 >= 1024u){ scal[1] = 4*t+2; scal[2] = 1024 - (int)G2; }
  if (G3 < 1024u && G3 + h3 >= 1024u){ scal[1] = 4*t+3; scal[2] = 1024 - (int)G3; }
  __syncthreads();
  const unsigned p = (unsigned)scal[1];
  const int r = scal[2];
  // gather pivot-bucket elements (full 64-bit keys)
  #pragma unroll
  for (int u2 = 0; u2 < 4; u2++){
    if ((uu[u2] >> 20) == p){
      int pos = atomicAdd(&scal[0], 1);
      lst[pos] = ((unsigned long long)uu[u2] << 32) | (unsigned)(~(4*t + u2));
    }
  }
  __syncthreads();
  const int cnt = scal[0];
  int pad = 1; while (pad < cnt) pad <<= 1;
  for (int m = t; m < pad; m += 1024) if (m >= cnt) lst[m] = 0ull;  // pad = smallest
  __syncthreads();
  for (int k = 2; k <= pad; k <<= 1){
    for (int j = k >> 1; j > 0; j >>= 1){
      for (int m = t; m < (pad >> 1); m += 1024){
        int i = 2*m - (m & (j-1));
        int l = i + j;
        unsigned long long a = lst[i], c = lst[l];
        if ((a > c) == ((i & k) == 0)){ lst[i] = c; lst[l] = a; }
      }
      __syncthreads();
    }
  }
  const unsigned long long thr = lst[pad - r];   // r-th largest in pivot bucket
  // ordered compaction: key64 >= thr <=> in top-1024 (keys distinct)
  __shared__ int ws2[16];
  int sel[4]; int cnt2 = 0;
  #pragma unroll
  for (int u2 = 0; u2 < 4; u2++){
    const int m = 4*t + u2;
    unsigned long long key = ((unsigned long long)uu[u2] << 32) | (unsigned)(~m);
    sel[u2] = (key >= thr) ? 1 : 0;
    cnt2 += sel[u2];
  }
  int incl = cnt2;
  #pragma unroll
  for (int d2 = 1; d2 < 64; d2 <<= 1){
    int v2 = __shfl_up(incl, d2);
    if (lane >= d2) incl += v2;
  }
  if (lane == 63) ws2[w] = incl;
  __syncthreads();
  int base = 0;
  #pragma unroll
  for (int ww = 0; ww < 16; ww++) if (ww < w) base += ws2[ww];
  int pos = base + incl - cnt2;
  #pragma unroll
  for (int u2 = 0; u2 < 4; u2++){
    if (sel[u2]) tidx[(size_t)b*K_ + pos++] = 4*t + u2;
  }
}

// ---------------- Kernel 3: gather + ONE of Q/K/V per block (set-split, 6 blocks/CU) ------
// grid (64 kt, 3 set, 8 b) = 1536 blocks: 3x the occupancy of the fused version on the
// latency-bound gather+GEMM (R0's proven lever). Gather is 3x-redundant but L3-hot.
// Q pre-scaled by QSCALE; V^T stored f16, keys PERMUTED within each 32-token block:
//   rel key k (0..31) -> pos 8*((k&15)>>2) + 4*((k>>4)&1) + (k&3)
__global__ __launch_bounds__(512) void qkv_kernel(
    const float* __restrict__ x, const int* __restrict__ tidx,
    const unsigned short* __restrict__ wh,
    const float* __restrict__ bq, const float* __restrict__ bk, const float* __restrict__ bv,
    float* __restrict__ xsp, unsigned short* __restrict__ qbf,
    unsigned short* __restrict__ kbf, unsigned short* __restrict__ vtb)
{
  __shared__ unsigned short xsb[16][256];   // f16 bits, swizzled 16B granules
  const int t = threadIdx.x;
  const int kt = blockIdx.x, set = blockIdx.y, b = blockIdx.z;
  const int tok0 = kt*16;
  { // gather: thread t -> token i = t&15, granule jg = t>>4 (8 channels)
    const int i = t & 15, jg = t >> 4;
    const int n = tidx[(size_t)b*K_ + tok0 + i];
    const float* xb = x + (size_t)b*C_*N_ + n;
    float v[8];
    #pragma unroll
    for (int u = 0; u < 8; u++) v[u] = xb[(size_t)(jg*8+u)*N_];
    if (set == 0){
      float* xr = xsp + ((size_t)b*K_ + tok0 + i)*C_ + jg*8;
      *(float4*)(xr)     = make_float4(v[0],v[1],v[2],v[3]);
      *(float4*)(xr + 4) = make_float4(v[4],v[5],v[6],v[7]);
    }
    uint4 pw;
    pw.x = hpk(v[0],v[1]); pw.y = hpk(v[2],v[3]);
    pw.z = hpk(v[4],v[5]); pw.w = hpk(v[6],v[7]);
    *(uint4*)((char*)&xsb[0][0] + i*512 + ((jg ^ (i&7))*16)) = pw;
  }
  __syncthreads();

  const int lane = t & 63, w = t >> 6;
  const int g = lane >> 4, c = lane & 15;
  const unsigned short* wset = wh + (size_t)set*65536;

  f32x4 acc0 = {0.f,0.f,0.f,0.f}, acc1 = {0.f,0.f,0.f,0.f};
  if (set == 2){
    #pragma unroll 1
    for (int ks = 0; ks < 8; ks++){
      half8 Xf = *(const half8*)((const char*)&xsb[0][0] + c*512 + (((4*ks+g) ^ (c&7))*16));
      half8 Wf0 = *(const half8*)(wset + (32*w + c)*C_ + ks*32 + 8*g);
      half8 Wf1 = *(const half8*)(wset + (32*w + 16 + c)*C_ + ks*32 + 8*g);
      acc0 = __builtin_amdgcn_mfma_f32_16x16x32_f16(Xf, Wf0, acc0, 0,0,0);
      acc1 = __builtin_amdgcn_mfma_f32_16x16x32_f16(Xf, Wf1, acc1, 0,0,0);
    }
  } else {
    #pragma unroll 1
    for (int ks = 0; ks < 8; ks++){
      half8 Xf = *(const half8*)((const char*)&xsb[0][0] + c*512 + (((4*ks+g) ^ (c&7))*16));
      half8 Wf0 = *(const half8*)(wset + (32*w + c)*C_ + ks*32 + 8*g);
      half8 Wf1 = *(const half8*)(wset + (32*w + 16 + c)*C_ + ks*32 + 8*g);
      acc0 = __builtin_amdgcn_mfma_f32_16x16x32_f16(Wf0, Xf, acc0, 0,0,0);
      acc1 = __builtin_amdgcn_mfma_f32_16x16x32_f16(Wf1, Xf, acc1, 0,0,0);
    }
  }

  const int bh = b*NH_ + w;   // head = wave index
  if (set < 2){
    // Q/K epilogue: lane (g,c): tok = tok0+c, d = 16j+4g+r (8B contiguous)
    const float* bias = set ? bk : bq;
    const float sc = set ? 1.f : QSCALE;
    unsigned short* dstb = set ? kbf : qbf;
    #pragma unroll
    for (int j=0;j<2;j++){
      const f32x4& a = j ? acc1 : acc0;
      float4 bb = *(const float4*)(bias + w*32 + 16*j + 4*g);
      unsigned lo = pk2((a[0]+bb.x)*sc, (a[1]+bb.y)*sc);
      unsigned hi = pk2((a[2]+bb.z)*sc, (a[3]+bb.w)*sc);
      unsigned short* dst = dstb + ((size_t)bh*K_ + tok0 + c)*HD_ + 16*j + 4*g;
      *(uint2*)dst = make_uint2(lo, hi);
    }
  } else {
    // V^T scatter, f16, key-permuted: lane holds tokens tok0+4g+{0..3} = rel 16*half+4g+r
    const int base32 = tok0 & ~31;
    const int half   = (tok0 >> 4) & 1;
    #pragma unroll
    for (int j=0;j<2;j++){
      const f32x4& a = j ? acc1 : acc0;
      const float bvv = bv[w*32 + 16*j + c];
      unsigned lo = hpk(a[0]+bvv, a[1]+bvv);
      unsigned hi = hpk(a[2]+bvv, a[3]+bvv);
      unsigned short* dst = vtb + ((size_t)bh*HD_ + 16*j + c)*K_ + base32 + 8*g + 4*half;
      *(uint2*)dst = make_uint2(lo, hi);
    }
  }
}

// ---------------- Kernel 4: MFMA flash attention, depth-2 register pipeline (R18 best) ----
// L computed on the matrix pipe: mfma(ONES, P) gives every lane Sum_k P[k][q].
// Grid flat = h + 8*(qt + 8*b). 8 waves = (sp,qq): split-K 2-way, merge by plain addition.
__global__ __launch_bounds__(512) void attn_kernel(
    const unsigned short* __restrict__ qbf, const unsigned short* __restrict__ kbf,
    const unsigned short* __restrict__ vtb, unsigned short* __restrict__ ob)
{
  __shared__ float po[4][64][19];   // [qq][lane][ot(16) | L0 | L1]; stride 19 -> <=2-way
  const int tid = threadIdx.x;
  const int t = tid & 63, w = tid >> 6;
  const int sp = w >> 2, qq = w & 3;
  const int flat = blockIdx.x;
  const int h = flat & 7;
  const int rest = flat >> 3;      // 0..63
  const int qt = rest & 7;
  const int b = rest >> 3;         // 0..7
  const int g = t >> 4, c = t & 15;
  const int bh = b*NH_ + h;
  const int q0 = qt*128 + qq*32;   // 32 q-rows per wave

  short8 Qf0 = *(const short8*)(qbf + ((size_t)bh*K_ + q0 + c)*HD_ + g*8);
  short8 Qf1 = *(const short8*)(qbf + ((size_t)bh*K_ + q0 + 16 + c)*HD_ + g*8);

  const int kbeg = sp*512;
  const unsigned short* kp  = kbf + (size_t)bh*K_*HD_ + (size_t)(kbeg + c)*HD_ + g*8;
  const unsigned short* vp0 = vtb + ((size_t)bh*HD_ + c)*K_ + kbeg + g*8;
  const unsigned short* vp1 = vp0 + (size_t)16*K_;

  const half4 ONES = {(_Float16)1.f, (_Float16)1.f, (_Float16)1.f, (_Float16)1.f};
  f32x4 ot00 = {0.f,0.f,0.f,0.f}, ot01 = {0.f,0.f,0.f,0.f};  // qi=0: dv 0..15, 16..31
  f32x4 ot10 = {0.f,0.f,0.f,0.f}, ot11 = {0.f,0.f,0.f,0.f};  // qi=1
  f32x4 otL0 = {0.f,0.f,0.f,0.f}, otL1 = {0.f,0.f,0.f,0.f};  // L accumulators

#define ATTN_STEP(K0c,K1c,V0c,V1c) do {                                           \
    f32x4 z = {0.f,0.f,0.f,0.f};                                                  \
    __builtin_amdgcn_s_setprio(1);                                                \
    f32x4 s00 = __builtin_amdgcn_mfma_f32_16x16x32_bf16(K0c, Qf0, z, 0, 0, 0);    \
    f32x4 s01 = __builtin_amdgcn_mfma_f32_16x16x32_bf16(K1c, Qf0, z, 0, 0, 0);    \
    f32x4 s10 = __builtin_amdgcn_mfma_f32_16x16x32_bf16(K0c, Qf1, z, 0, 0, 0);    \
    f32x4 s11 = __builtin_amdgcn_mfma_f32_16x16x32_bf16(K1c, Qf1, z, 0, 0, 0);    \
    __builtin_amdgcn_s_setprio(0);                                                \
    float p00[4], p01[4], p10[4], p11[4];                                         \
    _Pragma("unroll")                                                             \
    for (int r=0;r<4;r++){                                                        \
      p00[r] = EXPX(s00[r]); p01[r] = EXPX(s01[r]);                               \
      p10[r] = EXPX(s10[r]); p11[r] = EXPX(s11[r]);                               \
    }                                                                             \
    half4 P00 = pk4rtz(p00[0], p00[1], p00[2], p00[3]);                           \
    half4 P01 = pk4rtz(p01[0], p01[1], p01[2], p01[3]);                           \
    half4 P10 = pk4rtz(p10[0], p10[1], p10[2], p10[3]);                           \
    half4 P11 = pk4rtz(p11[0], p11[1], p11[2], p11[3]);                           \
    half4 A0lo = __builtin_shufflevector(V0c, V0c, 0, 1, 2, 3);                   \
    half4 A0hi = __builtin_shufflevector(V0c, V0c, 4, 5, 6, 7);                   \
    half4 A1lo = __builtin_shufflevector(V1c, V1c, 0, 1, 2, 3);                   \
    half4 A1hi = __builtin_shufflevector(V1c, V1c, 4, 5, 6, 7);                   \
    __builtin_amdgcn_s_setprio(1);                                                \
    ot00 = __builtin_amdgcn_mfma_f32_16x16x16f16(A0lo, P00, ot00, 0, 0, 0);       \
    ot00 = __builtin_amdgcn_mfma_f32_16x16x16f16(A0hi, P01, ot00, 0, 0, 0);       \
    ot01 = __builtin_amdgcn_mfma_f32_16x16x16f16(A1lo, P00, ot01, 0, 0, 0);       \
    ot01 = __builtin_amdgcn_mfma_f32_16x16x16f16(A1hi, P01, ot01, 0, 0, 0);       \
    ot10 = __builtin_amdgcn_mfma_f32_16x16x16f16(A0lo, P10, ot10, 0, 0, 0);       \
    ot10 = __builtin_amdgcn_mfma_f32_16x16x16f16(A0hi, P11, ot10, 0, 0, 0);       \
    ot11 = __builtin_amdgcn_mfma_f32_16x16x16f16(A1lo, P10, ot11, 0, 0, 0);       \
    ot11 = __builtin_amdgcn_mfma_f32_16x16x16f16(A1hi, P11, ot11, 0, 0, 0);       \
    otL0 = __builtin_amdgcn_mfma_f32_16x16x16f16(ONES, P00, otL0, 0, 0, 0);       \
    otL0 = __builtin_amdgcn_mfma_f32_16x16x16f16(ONES, P01, otL0, 0, 0, 0);       \
    otL1 = __builtin_amdgcn_mfma_f32_16x16x16f16(ONES, P10, otL1, 0, 0, 0);       \
    otL1 = __builtin_amdgcn_mfma_f32_16x16x16f16(ONES, P11, otL1, 0, 0, 0);       \
    __builtin_amdgcn_s_setprio(0);                                                \
  } while(0)

  // depth-2 register pipeline; prefetches past the region land in allocated workspace
  short8 K0a = *(const short8*)(kp);
  short8 K1a = *(const short8*)(kp + 16*HD_);
  half8  V0a = *(const half8*)(vp0);
  half8  V1a = *(const half8*)(vp1);
  kp += 32*HD_; vp0 += 32; vp1 += 32;
  short8 K0b = *(const short8*)(kp);
  short8 K1b = *(const short8*)(kp + 16*HD_);
  half8  V0b = *(const half8*)(vp0);
  half8  V1b = *(const half8*)(vp1);

  for (int it = 0; it < 16; it += 2){
    kp += 32*HD_; vp0 += 32; vp1 += 32;
    short8 K0n = *(const short8*)(kp);
    short8 K1n = *(const short8*)(kp + 16*HD_);
    half8  V0n = *(const half8*)(vp0);
    half8  V1n = *(const half8*)(vp1);
    ATTN_STEP(K0a, K1a, V0a, V1a);
    K0a = K0n; K1a = K1n; V0a = V0n; V1a = V1n;
    kp += 32*HD_; vp0 += 32; vp1 += 32;
    short8 K0m = *(const short8*)(kp);
    short8 K1m = *(const short8*)(kp + 16*HD_);
    half8  V0m = *(const half8*)(vp0);
    half8  V1m = *(const half8*)(vp1);
    ATTN_STEP(K0b, K1b, V0b, V1b);
    K0b = K0m; K1b = K1m; V0b = V0m; V1b = V1m;
  }
#undef ATTN_STEP

  if (sp == 1){
    float* d = po[qq][t];
    d[0]=ot00[0]; d[1]=ot00[1]; d[2]=ot00[2];  d[3]=ot00[3];
    d[4]=ot01[0]; d[5]=ot01[1]; d[6]=ot01[2];  d[7]=ot01[3];
    d[8]=ot10[0]; d[9]=ot10[1]; d[10]=ot10[2]; d[11]=ot10[3];
    d[12]=ot11[0];d[13]=ot11[1];d[14]=ot11[2]; d[15]=ot11[3];
    d[16]=otL0[0]; d[17]=otL1[0];
  }
  __syncthreads();
  if (sp == 0){
    const float* d = po[qq][t];
    ot00[0]+=d[0]; ot00[1]+=d[1]; ot00[2]+=d[2];  ot00[3]+=d[3];
    ot01[0]+=d[4]; ot01[1]+=d[5]; ot01[2]+=d[6];  ot01[3]+=d[7];
    ot10[0]+=d[8]; ot10[1]+=d[9]; ot10[2]+=d[10]; ot10[3]+=d[11];
    ot11[0]+=d[12];ot11[1]+=d[13];ot11[2]+=d[14]; ot11[3]+=d[15];
    const float L0 = otL0[0] + d[16];
    const float L1 = otL1[0] + d[17];
    const float i0 = 1.f / L0, i1 = 1.f / L1;
    unsigned short* o0 = ob + ((size_t)b*K_ + q0 + c)*C_ + h*HD_;
    unsigned short* o1 = ob + ((size_t)b*K_ + q0 + 16 + c)*C_ + h*HD_;
    *(uint2*)(o0 + 4*g)      = make_uint2(hpk(ot00[0]*i0, ot00[1]*i0), hpk(ot00[2]*i0, ot00[3]*i0));
    *(uint2*)(o0 + 16 + 4*g) = make_uint2(hpk(ot01[0]*i0, ot01[1]*i0), hpk(ot01[2]*i0, ot01[3]*i0));
    *(uint2*)(o1 + 4*g)      = make_uint2(hpk(ot10[0]*i1, ot10[1]*i1), hpk(ot10[2]*i1, ot10[3]*i1));
    *(uint2*)(o1 + 16 + 4*g) = make_uint2(hpk(ot11[0]*i1, ot11[1]*i1), hpk(ot11[2]*i1, ot11[3]*i1));
  }
}

// ---------------- Kernel 5: out-proj (f16 MFMA) + residual + LayerNorm + scatter ----------------
// 16-token tiles -> grid (64,8) = 512 blocks (2 per CU).
__global__ __launch_bounds__(512) void out_kernel(
    const unsigned short* __restrict__ ob, const float* __restrict__ xsp,
    const int* __restrict__ tidx, const unsigned short* __restrict__ woh, const float* __restrict__ bo,
    const float* __restrict__ lng, const float* __restrict__ lnb,
    float* __restrict__ out)
{
  __shared__ float red1[8][16], red2[8][16];
  __shared__ float mus[16], rss[16];
  __shared__ int nn[16];
  const int t = threadIdx.x;
  const int kt = blockIdx.x, b = blockIdx.y;
  const int tok0 = kt*16;
  const int lane = t & 63, w = t >> 6;
  const int g = lane >> 4, c = lane & 15;

  if (t < 16) nn[t] = tidx[(size_t)b*K_ + tok0 + t];

  f32x4 acc0 = {0.f,0.f,0.f,0.f}, acc1 = {0.f,0.f,0.f,0.f};

  const unsigned short* ob0 = ob + ((size_t)b*K_ + tok0)*C_;
  const unsigned short* wr0 = woh + (32*w + c)*C_;

  #pragma unroll 1
  for (int ks = 0; ks < 8; ks++){
    half8 Wf0 = *(const half8*)(wr0 + ks*32 + 8*g);
    half8 Wf1 = *(const half8*)(wr0 + 16*C_ + ks*32 + 8*g);
    half8 Of  = *(const half8*)(ob0 + (size_t)c*C_ + ks*32 + 8*g);
    acc0 = __builtin_amdgcn_mfma_f32_16x16x32_f16(Wf0, Of, acc0, 0,0,0);
    acc1 = __builtin_amdgcn_mfma_f32_16x16x32_f16(Wf1, Of, acc1, 0,0,0);
  }

  // bias + residual (fp32)
  const float* xr = xsp + ((size_t)b*K_ + tok0 + c)*C_ + 32*w + 4*g;
  {
    float4 bb0 = *(const float4*)(bo + 32*w + 4*g);
    float4 bb1 = *(const float4*)(bo + 32*w + 16 + 4*g);
    float4 xv0 = *(const float4*)(xr);
    float4 xv1 = *(const float4*)(xr + 16);
    acc0[0] += bb0.x + xv0.x; acc0[1] += bb0.y + xv0.y;
    acc0[2] += bb0.z + xv0.z; acc0[3] += bb0.w + xv0.w;
    acc1[0] += bb1.x + xv1.x; acc1[1] += bb1.y + xv1.y;
    acc1[2] += bb1.z + xv1.z; acc1[3] += bb1.w + xv1.w;
  }

  // LN partials: per token sum over this wave's 32 oc; g-groups share the token
  {
    float s1 = 0.f, s2 = 0.f;
    #pragma unroll
    for (int r=0;r<4;r++){ float y = acc0[r]; s1 += y; s2 += y*y; }
    #pragma unroll
    for (int r=0;r<4;r++){ float y = acc1[r]; s1 += y; s2 += y*y; }
    s1 += __shfl_xor(s1, 16); s2 += __shfl_xor(s2, 16);
    s1 += __shfl_xor(s1, 32); s2 += __shfl_xor(s2, 32);
    if (g == 0){ red1[w][c] = s1; red2[w][c] = s2; }
  }
  __syncthreads();
  if (t < 16){
    float a = 0.f, q2 = 0.f;
    #pragma unroll
    for (int ww=0;ww<8;ww++){ a += red1[ww][t]; q2 += red2[ww][t]; }
    float mu = a*(1.f/256.f);
    float var = q2*(1.f/256.f) - mu*mu;
    mus[t] = mu;
    rss[t] = rsqrtf(var + 1e-5f);
  }
  __syncthreads();

  // scale/shift + scatter
  const float mu = mus[c], rs = rss[c];
  const int n = nn[c];
  float* outb = out + (size_t)b*C_*N_;
  #pragma unroll
  for (int j=0;j<2;j++){
    const int oc0 = 32*w + 16*j + 4*g;
    float4 gvv = *(const float4*)(lng + oc0);
    float4 bvv = *(const float4*)(lnb + oc0);
    const f32x4& a = j ? acc1 : acc0;
    outb[(size_t)(oc0+0)*N_ + n] = (a[0]-mu)*rs*gvv.x + bvv.x;
    outb[(size_t)(oc0+1)*N_ + n] = (a[1]-mu)*rs*gvv.y + bvv.y;
    outb[(size_t)(oc0+2)*N_ + n] = (a[2]-mu)*rs*gvv.z + bvv.z;
    outb[(size_t)(oc0+3)*N_ + n] = (a[3]-mu)*rs*gvv.w + bvv.w;
  }
}

extern "C" void kernel_launch(void* const* d_in, const int* in_sizes, int n_in,
                              void* d_out, int out_size, void* d_ws, size_t ws_size,
                              hipStream_t stream)
{
  const float* x    = (const float*)d_in[0];
  const float* bmap = (const float*)d_in[1];
  const float* w1   = (const float*)d_in[2];
  const float* b1   = (const float*)d_in[3];
  const float* w2   = (const float*)d_in[4];
  const float* b2   = (const float*)d_in[5];
  const float* wq   = (const float*)d_in[6];
  const float* bq   = (const float*)d_in[7];
  const float* wk   = (const float*)d_in[8];
  const float* bk   = (const float*)d_in[9];
  const float* wv   = (const float*)d_in[10];
  const float* bv   = (const float*)d_in[11];
  const float* wo   = (const float*)d_in[12];
  const float* bo   = (const float*)d_in[13];
  const float* lng  = (const float*)d_in[14];
  const float* lnb  = (const float*)d_in[15];

  float* out = (float*)d_out;
  float* imp_out = out + (size_t)B_*C_*N_;   // importance is output #2, concatenated

  char* wsb = (char*)d_ws;
  int*   tidx = (int*)wsb;                                // 64 KB slot
  float* xsp  = (float*)(wsb + 65536);                    // [B,K,C] fp32, 8 MB
  unsigned short* ob16 = (unsigned short*)(xsp + (size_t)B_*K_*C_); // [B,K,C] f16, 4 MB (8 MB slot)
  unsigned short* qbf = ob16 + 2*(size_t)B_*K_*C_;        // [B,H,K,32] bf16, 4 MB
  unsigned short* kbf = qbf + (size_t)B_*NH_*K_*HD_;      // [B,H,K,32] bf16, 4 MB
  unsigned short* vtb = kbf + (size_t)B_*NH_*K_*HD_;      // [B,H,32,K] f16 key-permuted, 4 MB
  unsigned short* wh  = vtb + (size_t)B_*NH_*K_*HD_;      // [4][256][256] f16, 512 KB

  imp_kernel <<<dim3(1024),     dim3(256),  0, stream>>>(x, bmap, w1, b1, w2, b2, imp_out, out);
  topk_kernel<<<dim3(40),       dim3(1024), 0, stream>>>(imp_out, tidx, wq, wk, wv, wo, wh);
  qkv_kernel <<<dim3(64, 3, 8), dim3(512),  0, stream>>>(x, tidx, wh, bq, bk, bv, xsp, qbf, kbf, vtb);
  attn_kernel<<<dim3(512),      dim3(512),  0, stream>>>(qbf, kbf, vtb, ob16);
  out_kernel <<<dim3(64, 8),    dim3(512),  0, stream>>>(ob16, xsp, tidx, wh + 3*65536, bo, lng, lnb, out);
}